// Round 5
// baseline (192.693 us; speedup 1.0000x reference)
//
#include <hip/hip_runtime.h>
#include <math.h>

typedef unsigned short u16;
typedef unsigned int u32;
typedef __attribute__((ext_vector_type(8))) short short8;
typedef __attribute__((ext_vector_type(4))) short short4v;
typedef __attribute__((ext_vector_type(4))) float f32x4;

// ---------- helpers ----------
__device__ __forceinline__ u16 f2bf(float f) {
  union { float f; unsigned u; } x; x.f = f;
  unsigned r = x.u + 0x7FFFu + ((x.u >> 16) & 1u);   // RNE
  return (u16)(r >> 16);
}

__device__ __forceinline__ u32 asu(float f) {
  union { float f; u32 u; } x; x.f = f; return x.u;
}

// pack two floats -> two bf16 (round-half-up) in one u32: lo=a, hi=b
__device__ __forceinline__ u32 pack2bf(float a, float b) {
  return __builtin_amdgcn_perm(asu(b) + 0x8000u, asu(a) + 0x8000u, 0x07060302u);
}

// single-instruction packed f32->bf16 (RNE), lo=a hi=b  [T12 primitive]
__device__ __forceinline__ u32 cvtpk2bf(float a, float b) {
  u32 r;
  asm("v_cvt_pk_bf16_f32 %0, %1, %2" : "=v"(r) : "v"(a), "v"(b));
  return r;
}

__device__ __forceinline__ void gld_lds16(const void* g, void* l) {
  __builtin_amdgcn_global_load_lds(
      (const __attribute__((address_space(1))) unsigned int*)g,
      (__attribute__((address_space(3))) unsigned int*)l, 16, 0, 0);
}

// ---------- fused preprocessing ----------
// cast Xq/Xc row-major bf16 + convert weights to FRAGMENT-MAJOR bf16.
// Chunk (n4=n>>4, k5=k>>5) at ((n4*32)+k5)*512; within chunk element (n,k):
// addr = (k>>3)*128 + (n&15)*8 + (k&7)  (verified R11).
__global__ void pre_kernel(const float* __restrict__ q, const float* __restrict__ c,
                           const float* __restrict__ Wq, const float* __restrict__ Wkv,
                           const float* __restrict__ Wo,
                           u16* __restrict__ xq, u16* __restrict__ xc,
                           u16* __restrict__ WqF, u16* __restrict__ WkvF,
                           u16* __restrict__ WoF) {
  __shared__ float tile[32][33];
  int bx = blockIdx.x;
  int t = threadIdx.y * 32 + threadIdx.x;
  if (bx < 8192) {
    int i = bx * 256 + t;
    const float* src = q; u16* dst = xq;
    if (i >= 1048576) { i -= 1048576; src = c; dst = xc; }
    float4 v = ((const float4*)src)[i];
    ((uint2*)dst)[i] = make_uint2(
        (unsigned)f2bf(v.x) | ((unsigned)f2bf(v.y) << 16),
        (unsigned)f2bf(v.z) | ((unsigned)f2bf(v.w) << 16));
  } else {
    int g = bx - 8192;
    int gx = g & 127, gy = g >> 7;               // gy = k-tile in [0,32)
    const float* src; u16* dst; int N, n0;
    if (gx < 32)      { src = Wq;  dst = WqF;  N = 1024; n0 = gx * 32; }
    else if (gx < 96) { src = Wkv; dst = WkvF; N = 2048; n0 = (gx - 32) * 32; }
    else              { src = Wo;  dst = WoF;  N = 1024; n0 = (gx - 96) * 32; }
    int k0 = gy * 32;
    int tx = threadIdx.x, ty = threadIdx.y;      // (32,8)
#pragma unroll
    for (int i = 0; i < 4; ++i)
      tile[ty * 4 + i][tx] = src[(size_t)(k0 + ty * 4 + i) * N + n0 + tx];
    __syncthreads();
    int e = t * 4;
    int ch = e >> 9, rem = e & 511;
    int kg = (rem >> 7) & 3;          // k-group of 8
    int nl = (rem >> 3) & 15;         // n within 16
    int j0 = rem & 7;                 // 0 or 4
    int kk = kg * 8 + j0;
    int nn = ch * 16 + nl;
    u32 lo = pack2bf(tile[kk][nn], tile[kk + 1][nn]);
    u32 hi = pack2bf(tile[kk + 2][nn], tile[kk + 3][nn]);
    *(uint2*)(dst + (size_t)(((n0 >> 4) + ch) * 32 + gy) * 512 + rem) = make_uint2(lo, hi);
  }
}

// ---------- fused QKV GEMM: 768 blocks (3/CU resident), 256 thr, 128x128 ----------
// R5: BK=32 with BOTH operands staged through dbuf LDS via global_load_lds
// (A 2x8KB + B 2x8KB = 32KB -> same 33792B LDS block as R4, 3/CU, no tail).
// Removes the 8 per-wave B global loads from the K-loop critical path (the
// delta vs the 874-TF m97 reference structure). A chunk = 16 rows x 32 k,
// XOR swizzle pos = quad ^ ((row>>1)&3) -> <=2-way bank alias (free).
__global__ __launch_bounds__(256) void qkv_gemm(
    const u16* __restrict__ Xq, const u16* __restrict__ Xc,
    const u16* __restrict__ WqF, const u16* __restrict__ WkvF,
    const float* __restrict__ bq, const float* __restrict__ bkv,
    u16* __restrict__ qb, u16* __restrict__ kf, u16* __restrict__ vf,
    float qscale) {
  __shared__ __align__(16) u16 smem[16896];      // K-loop: A dbuf [0,8192)u16 + B dbuf [8192,16384)u16 / epilogue C-tile
  const int tid = threadIdx.x, lane = tid & 63, wave = tid >> 6;
  const int quad = lane >> 4, cl = lane & 15;
  const int wr = (wave >> 1) * 64, wc = (wave & 1) * 64;

  // XCD-aware 2D remap (assumes xcd = blockIdx.x % 8; bijective on 768)
  const int xcd = blockIdx.x & 7, pos = blockIdx.x >> 3;   // pos in [0,96)
  const u16 *A, *Bf; const float* bias; int m0, n0; bool isq;
  if (pos < 64) {   // KV chunk: 8m x 8n per XCD
    isq = false; A = Xc; Bf = WkvF; bias = bkv;
    m0 = ((xcd >> 1) * 8 + (pos >> 3)) * 128;
    n0 = ((xcd & 1) * 8 + (pos & 7)) * 128;
  } else {          // Q chunk: 4m x 8n per XCD
    int p = pos - 64;
    isq = true;  A = Xq; Bf = WqF;  bias = bq;
    m0 = (xcd * 4 + (p >> 3)) * 128;
    n0 = (p & 7) * 128;
  }
  const int n04 = n0 >> 4;

  // A staging geometry: chunk = 16 rows x 32 k (1KB); 8 chunks, 2/wave.
  // lane L -> row-in-chunk rA2=L>>2, stored k-slot L&3 holds global
  // k-group (L&3) ^ ((rA2>>1)&3)  [inverse of reader swizzle]
  const int rA2 = lane >> 2;
  const int kcs2 = ((lane & 3) ^ ((lane >> 3) & 3)) * 8;

  auto stageA = [&](int k0, int buf) {
    u16* As = smem + buf * 4096;
#pragma unroll
    for (int it = 0; it < 2; ++it) {
      int c = wave * 2 + it;
      gld_lds16(A + (size_t)(m0 + c * 16 + rA2) * 1024 + k0 + kcs2, As + c * 512);
    }
  };
  // B staging: 8 chunks of 1KB, frag-major source is chunk-linear; 2/wave
  auto stageB = [&](int k5, int buf) {
    u16* Bs = smem + 8192 + buf * 4096;
#pragma unroll
    for (int it = 0; it < 2; ++it) {
      int j = wave * 2 + it;
      gld_lds16(Bf + (size_t)((n04 + j) * 32 + k5) * 512 + lane * 8, Bs + j * 512);
    }
  };

  f32x4 acc[4][4] = {};

  stageA(0, 0);
  stageB(0, 0);
  __syncthreads();                               // drain stage0 (only uncovered drain)

  for (int i = 0; i < 32; ++i) {
    const int cur = i & 1;
    if (i < 31) { stageA((i + 1) * 32, cur ^ 1); stageB(i + 1, cur ^ 1); }
    const u16* As = smem + cur * 4096;
    const u16* Bs = smem + 8192 + cur * 4096;
    short8 bf[4];
#pragma unroll
    for (int ni = 0; ni < 4; ++ni)
      bf[ni] = *(const short8*)(Bs + (((wave & 1) * 4 + ni) * 512) + lane * 8);
    short8 af[4];
#pragma unroll
    for (int mi = 0; mi < 4; ++mi) {
      int row = wr + mi * 16 + cl;               // row&15 == cl
      af[mi] = *(const short8*)(As + (row >> 4) * 512 + cl * 32 +
                                ((quad ^ ((cl >> 1) & 3)) * 8));
    }
#pragma unroll
    for (int mi = 0; mi < 4; ++mi)
#pragma unroll
      for (int ni = 0; ni < 4; ++ni)
        acc[mi][ni] = __builtin_amdgcn_mfma_f32_16x16x32_bf16(af[mi], bf[ni], acc[mi][ni], 0, 0, 0);
    __syncthreads();   // reads of cur done; DMA(nxt) drained
  }

  if (isq) {
#pragma unroll
    for (int mi = 0; mi < 4; ++mi)
#pragma unroll
      for (int ni = 0; ni < 4; ++ni)
#pragma unroll
        for (int r = 0; r < 4; ++r) {
          int row = m0 + wr + mi * 16 + quad * 4 + r;
          int col = n0 + wc + ni * 16 + cl;
          qb[(size_t)row * 1024 + col] = f2bf((acc[mi][ni][r] + bias[col]) * qscale);
        }
    return;
  }

  const int b = m0 >> 11, kt0 = (m0 & 2047) >> 6;
  const bool kreg = (n0 < 1024);
  if (kreg) {
    // K-tile -> LDS [t][d], stride 132 (scalar b16 stores; b128 frag reads)
#pragma unroll
    for (int mi = 0; mi < 4; ++mi)
#pragma unroll
      for (int ni = 0; ni < 4; ++ni)
#pragma unroll
        for (int r = 0; r < 4; ++r)
          smem[(wr + mi * 16 + quad * 4 + r) * 132 + wc + ni * 16 + cl] =
              f2bf(acc[mi][ni][r] + bias[n0 + wc + ni * 16 + cl]);
    __syncthreads();
#pragma unroll
    for (int i = 0; i < 8; ++i) {
      int c = i * 4 + wave;                       // 32 chunks
      int hs = c >> 4, ts = (c >> 3) & 1, ks = (c >> 2) & 1, idx = c & 3;
      int h = (n0 >> 6) + hs;
      size_t bhkt = ((size_t)((b * 16 + h) * 32 + kt0 + ts)) * 4096;
      short8 v = *(const short8*)(smem + (ts * 64 + idx * 16 + cl) * 132 +
                                  hs * 64 + ks * 32 + quad * 8);
      *(short8*)(kf + bhkt + (size_t)(ks * 4 + idx) * 512 + lane * 8) = v;
    }
  } else {
    // V-tile -> LDS transposed [d][t], stride 132, then emit relabeled V^T A-frags
#pragma unroll
    for (int mi = 0; mi < 4; ++mi)
#pragma unroll
      for (int ni = 0; ni < 4; ++ni) {
        float v0 = acc[mi][ni][0] + bias[n0 + wc + ni * 16 + cl];
        float v1 = acc[mi][ni][1] + bias[n0 + wc + ni * 16 + cl];
        float v2 = acc[mi][ni][2] + bias[n0 + wc + ni * 16 + cl];
        float v3 = acc[mi][ni][3] + bias[n0 + wc + ni * 16 + cl];
        *(uint2*)(smem + (wc + ni * 16 + cl) * 132 + wr + mi * 16 + quad * 4) =
            make_uint2(pack2bf(v0, v1), pack2bf(v2, v3));
      }
    __syncthreads();
#pragma unroll
    for (int i = 0; i < 8; ++i) {
      int c = i * 4 + wave;
      int hs = c >> 4, ts = (c >> 3) & 1, ks = (c >> 2) & 1, idx = c & 3;
      int h = ((n0 - 1024) >> 6) + hs;
      size_t bhkt = ((size_t)((b * 16 + h) * 32 + kt0 + ts)) * 4096;
      // k-slot j<4: t = ts*64 + ks*32 + quad*4 + j ; j>=4: +16
      const u16* src = smem + (hs * 64 + idx * 16 + cl) * 132 + ts * 64 + ks * 32 + quad * 4;
      short8 v;
      *(short4v*)&v       = *(const short4v*)(src);
      *((short4v*)&v + 1) = *(const short4v*)(src + 16);
      *(short8*)(vf + bhkt + (size_t)(ks * 4 + idx) * 512 + lane * 8) = v;
    }
  }
}

// ---------- O-proj: 512 blocks, 256 thr, 64x128 tiles ----------
// R2 (measured win): B staged via gld_lds dbuf + XCD remap. 48KB -> 3/CU,
// 512 blocks = 2/CU resident, no tail. Unchanged.
__global__ __launch_bounds__(256) void o_gemm(
    const u16* __restrict__ A, const u16* __restrict__ Bf,
    const float* __restrict__ bias, float* __restrict__ Cm) {
  __shared__ __align__(16) u16 smem[24576];   // [0,8192): A dbuf | [8192,24576): B dbuf
  const int tid = threadIdx.x, lane = tid & 63, wave = tid >> 6;
  const int quad = lane >> 4, cl = lane & 15;
  const int xcd = blockIdx.x & 7, pos = blockIdx.x >> 3;   // pos in [0,64)
  const int m0 = (xcd * 8 + (pos >> 3)) * 64, n0 = (pos & 7) * 128;
  const int wr = (wave >> 1) * 32, wc = (wave & 1) * 64;
  const int n04 = n0 >> 4;

  const int rA = lane >> 3;
  const int kcs = ((lane & 7) ^ rA) * 8;
  const int r7 = cl & 7;

  auto stageA = [&](int k0, int buf) {
    u16* As = smem + buf * 4096;
#pragma unroll
    for (int it = 0; it < 2; ++it) {
      int chunk = wave * 2 + it;
      gld_lds16(A + (size_t)(m0 + chunk * 8 + rA) * 1024 + k0 + kcs, As + chunk * 512);
    }
  };
  auto stageB = [&](int k0, int buf) {
    u16* Bs = smem + 8192 + buf * 8192;
    const int k05 = k0 >> 5;
#pragma unroll
    for (int it = 0; it < 4; ++it) {
      int c = it * 4 + wave;
      int j = c >> 1, ks = c & 1;
      gld_lds16(Bf + (size_t)((n04 + j) * 32 + k05 + ks) * 512 + lane * 8, Bs + c * 512);
    }
  };

  f32x4 acc[2][4] = {};

  stageA(0, 0);
  stageB(0, 0);
  __syncthreads();

  for (int i = 0; i < 16; ++i) {
    const int k0 = i * 64;
    const int cur = i & 1;
    if (i < 15) { stageA(k0 + 64, cur ^ 1); stageB(k0 + 64, cur ^ 1); }
    const u16* As = smem + cur * 4096;
    const u16* Bs = smem + 8192 + cur * 8192;
    short8 bf[2][4];
#pragma unroll
    for (int ks = 0; ks < 2; ++ks)
#pragma unroll
      for (int ni = 0; ni < 4; ++ni)
        bf[ks][ni] = *(const short8*)(Bs + (size_t)((((wave & 1) * 4 + ni) * 2 + ks) * 512) + lane * 8);
#pragma unroll
    for (int ks = 0; ks < 2; ++ks) {
      short8 af[2];
#pragma unroll
      for (int mi = 0; mi < 2; ++mi) {
        int row = wr + mi * 16 + cl;
        af[mi] = *(const short8*)(As + (row >> 3) * 512 + r7 * 64 +
                                  (((ks << 2) | quad) ^ r7) * 8);
      }
#pragma unroll
      for (int mi = 0; mi < 2; ++mi)
#pragma unroll
        for (int ni = 0; ni < 4; ++ni)
          acc[mi][ni] = __builtin_amdgcn_mfma_f32_16x16x32_bf16(af[mi], bf[ks][ni], acc[mi][ni], 0, 0, 0);
    }
    __syncthreads();
  }
#pragma unroll
  for (int mi = 0; mi < 2; ++mi)
#pragma unroll
    for (int ni = 0; ni < 4; ++ni)
#pragma unroll
      for (int r = 0; r < 4; ++r) {
        int row = m0 + wr + mi * 16 + quad * 4 + r;
        int col = n0 + wc + ni * 16 + cl;
        Cm[(size_t)row * 1024 + col] = acc[mi][ni][r] + bias[col];
      }
}

// ---------- flash attention: 512 blocks x 512 thr (8 waves), 128 q/block ----------
// R3 structure (halved K/V DMA traffic). Unchanged this round.
__global__ __launch_bounds__(512, 4) void flash_attn(
    const u16* __restrict__ qb, const u16* __restrict__ kf,
    const u16* __restrict__ vf, u16* __restrict__ outp) {
  __shared__ __align__(16) u16 kv[2][16 * 512];    // [buf][K chunks 0-7 | V chunks 8-15]
  const int tid = threadIdx.x, lane = tid & 63, wave = tid >> 6;   // wave in [0,8)
  const int quad = lane >> 4, cl = lane & 15;
  const int id = blockIdx.x;                       // 512 blocks
  const int h = (id & 7) | (((id >> 3) & 1) << 3); // XCD-aware: id%8 = h%8
  const int b = (id >> 4) & 1;
  const int qt = id >> 5;                          // [0,16), 128 q rows each

  const int qrow0 = b * 2048 + qt * 128 + wave * 16;
  short8 bq[2];   // Q as B-operand: B[n=cl][k=quad*8+j]
#pragma unroll
  for (int ks = 0; ks < 2; ++ks)
    bq[ks] = *(const short8*)(qb + (size_t)(qrow0 + cl) * 1024 + h * 64 + ks * 32 + quad * 8);

  short8 ones;    // all-ones bf16 A-fragment for the l-MFMA
#pragma unroll
  for (int j = 0; j < 8; ++j) ones[j] = (short)0x3F80;

  const u16* kfb = kf + (size_t)((b * 16 + h) * 32) * 4096;
  const u16* vfb = vf + (size_t)((b * 16 + h) * 32) * 4096;

  // 16 chunks/tile, 8 waves -> 2 chunks per wave (c<8: K chunk c; else V c-8)
  auto stage = [&](int kt, int buf) {
#pragma unroll
    for (int i = 0; i < 2; ++i) {
      int c = wave * 2 + i;
      const u16* src = (c < 8) ? (kfb + (size_t)kt * 4096 + c * 512)
                               : (vfb + (size_t)kt * 4096 + (c - 8) * 512);
      gld_lds16(src + lane * 8, &kv[buf][c * 512]);
    }
  };

  f32x4 o_acc[4] = {};   // O^T: row d = nd*16+quad*4+r, col m = cl
  f32x4 l_acc = {};      // denominator: every row of D = sum_k P[k][cl]

  stage(0, 0);
  __syncthreads();

#pragma unroll 1
  for (int kt = 0; kt < 32; ++kt) {
    const int cur = kt & 1, nxt = cur ^ 1;
    if (kt < 31) stage(kt + 1, nxt);           // DMA overlaps this iter's compute
    const u16* kb = &kv[cur][0];
    const u16* vb = &kv[cur][8 * 512];
    f32x4 st[4] = {};
    __builtin_amdgcn_s_setprio(1);
#pragma unroll
    for (int ks = 0; ks < 2; ++ks)
#pragma unroll
      for (int ni = 0; ni < 4; ++ni) {
        short8 ak = *(const short8*)(kb + (ks * 4 + ni) * 512 + lane * 8);
        st[ni] = __builtin_amdgcn_mfma_f32_16x16x32_bf16(ak, bq[ks], st[ni], 0, 0, 0);
      }
    __builtin_amdgcn_s_setprio(0);
    // issue V-frag reads NOW: ~120cy LDS latency hides under the exp/pack VALU
    short8 av[2][4];
#pragma unroll
    for (int ks = 0; ks < 2; ++ks)
#pragma unroll
      for (int nd = 0; nd < 4; ++nd)
        av[ks][nd] = *(const short8*)(vb + (ks * 4 + nd) * 512 + lane * 8);
    u32 bp[2][4];
#pragma unroll
    for (int ni = 0; ni < 4; ++ni) {
      float p0 = __builtin_amdgcn_exp2f(st[ni][0]);
      float p1 = __builtin_amdgcn_exp2f(st[ni][1]);
      float p2 = __builtin_amdgcn_exp2f(st[ni][2]);
      float p3 = __builtin_amdgcn_exp2f(st[ni][3]);
      bp[ni >> 1][(ni & 1) * 2 + 0] = cvtpk2bf(p0, p1);
      bp[ni >> 1][(ni & 1) * 2 + 1] = cvtpk2bf(p2, p3);
    }
    __builtin_amdgcn_s_setprio(1);
#pragma unroll
    for (int ks = 0; ks < 2; ++ks) {
      short8 pb;
      *(u32*)&pb     = bp[ks][0];
      ((u32*)&pb)[1] = bp[ks][1];
      ((u32*)&pb)[2] = bp[ks][2];
      ((u32*)&pb)[3] = bp[ks][3];
#pragma unroll
      for (int nd = 0; nd < 4; ++nd)
        o_acc[nd] = __builtin_amdgcn_mfma_f32_16x16x32_bf16(av[ks][nd], pb, o_acc[nd], 0, 0, 0);
      // denominator on the matrix pipe: D[m][cl] += sum_k 1*P[k][cl]
      l_acc = __builtin_amdgcn_mfma_f32_16x16x32_bf16(ones, pb, l_acc, 0, 0, 0);
    }
    __builtin_amdgcn_s_setprio(0);
    __syncthreads();   // waves done reading cur; DMA(nxt) drained
  }
  float inv = 1.f / l_acc[0];   // all rows identical; lane holds col cl
  // per-wave scratch: 16 rows x 68 u16; 8 waves span kv[0]+kv[1] (dead now,
  // each wave reads only its own region -> no cross-wave hazard)
  u16* Ow = &kv[0][wave * 16 * 68];
#pragma unroll
  for (int nd = 0; nd < 4; ++nd)
#pragma unroll
    for (int r2 = 0; r2 < 2; ++r2)
      *(u32*)(Ow + cl * 68 + nd * 16 + quad * 4 + r2 * 2) =
          cvtpk2bf(o_acc[nd][r2 * 2] * inv, o_acc[nd][r2 * 2 + 1] * inv);
#pragma unroll
  for (int half = 0; half < 2; ++half) {
    int row = half * 8 + (lane >> 3);
    int d0 = (lane & 7) * 8;
    short8 ov = *(const short8*)(Ow + row * 68 + d0);
    *(short8*)(outp + (size_t)(qrow0 + row) * 1024 + h * 64 + d0) = ov;
  }
}

// ---------- launch ----------
extern "C" void kernel_launch(void* const* d_in, const int* in_sizes, int n_in,
                              void* d_out, int out_size, void* d_ws, size_t ws_size,
                              hipStream_t stream) {
  const float* query   = (const float*)d_in[0];
  const float* context = (const float*)d_in[1];
  const float* Wq  = (const float*)d_in[2];
  const float* bq  = (const float*)d_in[3];
  const float* Wkv = (const float*)d_in[4];
  const float* bkv = (const float*)d_in[5];
  const float* Wo  = (const float*)d_in[6];
  const float* bo  = (const float*)d_in[7];
  float* out = (float*)d_out;

  char* ws = (char*)d_ws;
  size_t off = 0;
  auto alloc = [&](size_t bytes) {
    char* p = ws + off;
    off += (bytes + 255) & ~(size_t)255;
    return p;
  };
  u16* buf0 = (u16*)alloc(4096ull * 1024 * 2);   // Xq -> attn_out
  u16* xcb  = (u16*)alloc(4096ull * 1024 * 2);   // Xc
  u16* WqF  = (u16*)alloc(1024ull * 1024 * 2);   // frag-major weights
  u16* WkvF = (u16*)alloc(2048ull * 1024 * 2);
  u16* WoF  = (u16*)alloc(1024ull * 1024 * 2);
  u16* qb   = (u16*)alloc(4096ull * 1024 * 2);
  u16* kfr  = (u16*)alloc(4ull * 1024 * 1024 * 2);
  u16* vfr  = (u16*)alloc(4ull * 1024 * 1024 * 2);

  const float QSCALE = 0.125f * 1.44269504f;  // 1/sqrt(64) * log2(e)

  pre_kernel<<<12288, dim3(32, 8), 0, stream>>>(query, context, Wq, Wkv, Wo,
                                                buf0, xcb, WqF, WkvF, WoF);
  qkv_gemm<<<768, 256, 0, stream>>>(buf0, xcb, WqF, WkvF, bq, bkv,
                                    qb, kfr, vfr, QSCALE);
  flash_attn<<<512, 512, 0, stream>>>(qb, kfr, vfr, buf0);
  o_gemm<<<512, 256, 0, stream>>>(buf0, WoF, bo, out);
}

// Round 6
// 182.677 us; speedup vs baseline: 1.0548x; 1.0548x over previous
//
#include <hip/hip_runtime.h>
#include <math.h>

typedef unsigned short u16;
typedef unsigned int u32;
typedef __attribute__((ext_vector_type(8))) short short8;
typedef __attribute__((ext_vector_type(4))) short short4v;
typedef __attribute__((ext_vector_type(4))) float f32x4;

// ---------- helpers ----------
__device__ __forceinline__ u16 f2bf(float f) {
  union { float f; unsigned u; } x; x.f = f;
  unsigned r = x.u + 0x7FFFu + ((x.u >> 16) & 1u);   // RNE
  return (u16)(r >> 16);
}

__device__ __forceinline__ u32 asu(float f) {
  union { float f; u32 u; } x; x.f = f; return x.u;
}

// pack two floats -> two bf16 (round-half-up) in one u32: lo=a, hi=b
__device__ __forceinline__ u32 pack2bf(float a, float b) {
  return __builtin_amdgcn_perm(asu(b) + 0x8000u, asu(a) + 0x8000u, 0x07060302u);
}

// single-instruction packed f32->bf16 (RNE), lo=a hi=b  [T12 primitive]
__device__ __forceinline__ u32 cvtpk2bf(float a, float b) {
  u32 r;
  asm("v_cvt_pk_bf16_f32 %0, %1, %2" : "=v"(r) : "v"(a), "v"(b));
  return r;
}

__device__ __forceinline__ void gld_lds16(const void* g, void* l) {
  __builtin_amdgcn_global_load_lds(
      (const __attribute__((address_space(1))) unsigned int*)g,
      (__attribute__((address_space(3))) unsigned int*)l, 16, 0, 0);
}

// ---------- fused preprocessing ----------
// cast Xq/Xc row-major bf16 + convert weights to FRAGMENT-MAJOR bf16.
// Chunk (n4=n>>4, k5=k>>5) at ((n4*32)+k5)*512; within chunk element (n,k):
// addr = (k>>3)*128 + (n&15)*8 + (k&7)  (verified R11).
__global__ void pre_kernel(const float* __restrict__ q, const float* __restrict__ c,
                           const float* __restrict__ Wq, const float* __restrict__ Wkv,
                           const float* __restrict__ Wo,
                           u16* __restrict__ xq, u16* __restrict__ xc,
                           u16* __restrict__ WqF, u16* __restrict__ WkvF,
                           u16* __restrict__ WoF) {
  __shared__ float tile[32][33];
  int bx = blockIdx.x;
  int t = threadIdx.y * 32 + threadIdx.x;
  if (bx < 8192) {
    int i = bx * 256 + t;
    const float* src = q; u16* dst = xq;
    if (i >= 1048576) { i -= 1048576; src = c; dst = xc; }
    float4 v = ((const float4*)src)[i];
    ((uint2*)dst)[i] = make_uint2(
        (unsigned)f2bf(v.x) | ((unsigned)f2bf(v.y) << 16),
        (unsigned)f2bf(v.z) | ((unsigned)f2bf(v.w) << 16));
  } else {
    int g = bx - 8192;
    int gx = g & 127, gy = g >> 7;               // gy = k-tile in [0,32)
    const float* src; u16* dst; int N, n0;
    if (gx < 32)      { src = Wq;  dst = WqF;  N = 1024; n0 = gx * 32; }
    else if (gx < 96) { src = Wkv; dst = WkvF; N = 2048; n0 = (gx - 32) * 32; }
    else              { src = Wo;  dst = WoF;  N = 1024; n0 = (gx - 96) * 32; }
    int k0 = gy * 32;
    int tx = threadIdx.x, ty = threadIdx.y;      // (32,8)
#pragma unroll
    for (int i = 0; i < 4; ++i)
      tile[ty * 4 + i][tx] = src[(size_t)(k0 + ty * 4 + i) * N + n0 + tx];
    __syncthreads();
    int e = t * 4;
    int ch = e >> 9, rem = e & 511;
    int kg = (rem >> 7) & 3;          // k-group of 8
    int nl = (rem >> 3) & 15;         // n within 16
    int j0 = rem & 7;                 // 0 or 4
    int kk = kg * 8 + j0;
    int nn = ch * 16 + nl;
    u32 lo = pack2bf(tile[kk][nn], tile[kk + 1][nn]);
    u32 hi = pack2bf(tile[kk + 2][nn], tile[kk + 3][nn]);
    *(uint2*)(dst + (size_t)(((n0 >> 4) + ch) * 32 + gy) * 512 + rem) = make_uint2(lo, hi);
  }
}

// ---------- fused QKV GEMM: 768 blocks (3/CU resident), 256 thr, 128x128 ----------
// R6 = R4 (BK=64, A dbuf LDS, direct B, XCD remap, 16 barriers, no tail)
// + B software-pipelined into REGISTERS: prefetch B(i+1) issued alongside
// stageA(i+1); the compiler's pre-barrier vmcnt(0) drain (already required
// by the A-DMA) guarantees arrival before the next compute phase. Static
// double-set bA/bB with 2x-unrolled body (rule #20: no runtime-indexed
// vector arrays). launch_bounds(256,3) pins VGPR for 3 waves/SIMD.
__global__ __launch_bounds__(256, 3) void qkv_gemm(
    const u16* __restrict__ Xq, const u16* __restrict__ Xc,
    const u16* __restrict__ WqF, const u16* __restrict__ WkvF,
    const float* __restrict__ bq, const float* __restrict__ bkv,
    u16* __restrict__ qb, u16* __restrict__ kf, u16* __restrict__ vf,
    float qscale) {
  __shared__ __align__(16) u16 smem[16896];      // K-loop: As dbuf 2x8192 / epilogue: C-tile
  const int tid = threadIdx.x, lane = tid & 63, wave = tid >> 6;
  const int quad = lane >> 4, cl = lane & 15;
  const int wr = (wave >> 1) * 64, wc = (wave & 1) * 64;

  // XCD-aware 2D remap (assumes xcd = blockIdx.x % 8; bijective on 768)
  const int xcd = blockIdx.x & 7, pos = blockIdx.x >> 3;   // pos in [0,96)
  const u16 *A, *Bf; const float* bias; int m0, n0; bool isq;
  if (pos < 64) {   // KV chunk: 8m x 8n per XCD
    isq = false; A = Xc; Bf = WkvF; bias = bkv;
    m0 = ((xcd >> 1) * 8 + (pos >> 3)) * 128;
    n0 = ((xcd & 1) * 8 + (pos & 7)) * 128;
  } else {          // Q chunk: 4m x 8n per XCD
    int p = pos - 64;
    isq = true;  A = Xq; Bf = WqF;  bias = bq;
    m0 = (xcd * 4 + (p >> 3)) * 128;
    n0 = (p & 7) * 128;
  }
  const int bn4 = (n0 + wc) >> 4;

  const int rA = lane >> 3;
  const int kcs = ((lane & 7) ^ rA) * 8;         // swizzled source k within 64
  const int r7 = cl & 7;                          // reader row&7

  // stage BK=64 A-tile for k0 into buffer buf (16 chunks, 4/wave)
  auto stageA = [&](int k0, int buf) {
    u16* As = smem + buf * 8192;
#pragma unroll
    for (int it = 0; it < 4; ++it) {
      int chunk = it * 4 + wave;
      gld_lds16(A + (size_t)(m0 + chunk * 8 + rA) * 1024 + k0 + kcs, As + chunk * 512);
    }
  };

  f32x4 acc[4][4] = {};
  short8 bA[2][4], bB[2][4];

  // B-frag register prefetch for k-tile k05 (=k0>>5)
  auto loadB = [&](short8 (&dst)[2][4], int k05) {
#pragma unroll
    for (int ks = 0; ks < 2; ++ks)
#pragma unroll
      for (int ni = 0; ni < 4; ++ni)
        dst[ks][ni] = *(const short8*)(Bf + (size_t)((bn4 + ni) * 32 + k05 + ks) * 512 + lane * 8);
  };

  auto compute = [&](const u16* As, short8 (&breg)[2][4]) {
#pragma unroll
    for (int ks = 0; ks < 2; ++ks) {
      short8 af[4];
#pragma unroll
      for (int mi = 0; mi < 4; ++mi) {
        int row = wr + mi * 16 + cl;
        af[mi] = *(const short8*)(As + (row >> 3) * 512 + r7 * 64 +
                                  (((ks << 2) | quad) ^ r7) * 8);
      }
#pragma unroll
      for (int mi = 0; mi < 4; ++mi)
#pragma unroll
        for (int ni = 0; ni < 4; ++ni)
          acc[mi][ni] = __builtin_amdgcn_mfma_f32_16x16x32_bf16(af[mi], breg[ks][ni], acc[mi][ni], 0, 0, 0);
    }
  };

  stageA(0, 0);
  loadB(bA, 0);
  __syncthreads();                               // drain stage0

#pragma unroll 1
  for (int ii = 0; ii < 8; ++ii) {
    const int i = ii * 2;
    // even iter: consume bA from buf0; prefetch iter i+1 (A->LDS buf1, B->bB)
    stageA((i + 1) * 64, 1);
    loadB(bB, (i + 1) * 2);
    compute(smem, bA);
    __syncthreads();   // reads of buf0 done; DMA(buf1)+bB drained
    // odd iter: consume bB from buf1; prefetch iter i+2 (A->LDS buf0, B->bA)
    const int j = i + 1;
    if (j < 15) { stageA((j + 1) * 64, 0); loadB(bA, (j + 1) * 2); }
    compute(smem + 8192, bB);
    __syncthreads();   // reads of buf1 done; DMA(buf0)+bA drained
  }

  if (isq) {
#pragma unroll
    for (int mi = 0; mi < 4; ++mi)
#pragma unroll
      for (int ni = 0; ni < 4; ++ni)
#pragma unroll
        for (int r = 0; r < 4; ++r) {
          int row = m0 + wr + mi * 16 + quad * 4 + r;
          int col = n0 + wc + ni * 16 + cl;
          qb[(size_t)row * 1024 + col] = f2bf((acc[mi][ni][r] + bias[col]) * qscale);
        }
    return;
  }

  const int b = m0 >> 11, kt0 = (m0 & 2047) >> 6;
  const bool kreg = (n0 < 1024);
  if (kreg) {
    // K-tile -> LDS [t][d], stride 132 (scalar b16 stores; b128 frag reads)
#pragma unroll
    for (int mi = 0; mi < 4; ++mi)
#pragma unroll
      for (int ni = 0; ni < 4; ++ni)
#pragma unroll
        for (int r = 0; r < 4; ++r)
          smem[(wr + mi * 16 + quad * 4 + r) * 132 + wc + ni * 16 + cl] =
              f2bf(acc[mi][ni][r] + bias[n0 + wc + ni * 16 + cl]);
    __syncthreads();
#pragma unroll
    for (int i = 0; i < 8; ++i) {
      int c = i * 4 + wave;                       // 32 chunks
      int hs = c >> 4, ts = (c >> 3) & 1, ks = (c >> 2) & 1, idx = c & 3;
      int h = (n0 >> 6) + hs;
      size_t bhkt = ((size_t)((b * 16 + h) * 32 + kt0 + ts)) * 4096;
      short8 v = *(const short8*)(smem + (ts * 64 + idx * 16 + cl) * 132 +
                                  hs * 64 + ks * 32 + quad * 8);
      *(short8*)(kf + bhkt + (size_t)(ks * 4 + idx) * 512 + lane * 8) = v;
    }
  } else {
    // V-tile -> LDS transposed [d][t], stride 132, then emit relabeled V^T A-frags
#pragma unroll
    for (int mi = 0; mi < 4; ++mi)
#pragma unroll
      for (int ni = 0; ni < 4; ++ni) {
        float v0 = acc[mi][ni][0] + bias[n0 + wc + ni * 16 + cl];
        float v1 = acc[mi][ni][1] + bias[n0 + wc + ni * 16 + cl];
        float v2 = acc[mi][ni][2] + bias[n0 + wc + ni * 16 + cl];
        float v3 = acc[mi][ni][3] + bias[n0 + wc + ni * 16 + cl];
        *(uint2*)(smem + (wc + ni * 16 + cl) * 132 + wr + mi * 16 + quad * 4) =
            make_uint2(pack2bf(v0, v1), pack2bf(v2, v3));
      }
    __syncthreads();
#pragma unroll
    for (int i = 0; i < 8; ++i) {
      int c = i * 4 + wave;
      int hs = c >> 4, ts = (c >> 3) & 1, ks = (c >> 2) & 1, idx = c & 3;
      int h = ((n0 - 1024) >> 6) + hs;
      size_t bhkt = ((size_t)((b * 16 + h) * 32 + kt0 + ts)) * 4096;
      // k-slot j<4: t = ts*64 + ks*32 + quad*4 + j ; j>=4: +16
      const u16* src = smem + (hs * 64 + idx * 16 + cl) * 132 + ts * 64 + ks * 32 + quad * 4;
      short8 v;
      *(short4v*)&v       = *(const short4v*)(src);
      *((short4v*)&v + 1) = *(const short4v*)(src + 16);
      *(short8*)(vf + bhkt + (size_t)(ks * 4 + idx) * 512 + lane * 8) = v;
    }
  }
}

// ---------- O-proj: 512 blocks, 256 thr, 64x128 tiles ----------
// R2 (measured win): B staged via gld_lds dbuf + XCD remap. 48KB -> 3/CU,
// 512 blocks = 2/CU resident, no tail. Unchanged.
__global__ __launch_bounds__(256) void o_gemm(
    const u16* __restrict__ A, const u16* __restrict__ Bf,
    const float* __restrict__ bias, float* __restrict__ Cm) {
  __shared__ __align__(16) u16 smem[24576];   // [0,8192): A dbuf | [8192,24576): B dbuf
  const int tid = threadIdx.x, lane = tid & 63, wave = tid >> 6;
  const int quad = lane >> 4, cl = lane & 15;
  const int xcd = blockIdx.x & 7, pos = blockIdx.x >> 3;   // pos in [0,64)
  const int m0 = (xcd * 8 + (pos >> 3)) * 64, n0 = (pos & 7) * 128;
  const int wr = (wave >> 1) * 32, wc = (wave & 1) * 64;
  const int n04 = n0 >> 4;

  const int rA = lane >> 3;
  const int kcs = ((lane & 7) ^ rA) * 8;
  const int r7 = cl & 7;

  auto stageA = [&](int k0, int buf) {
    u16* As = smem + buf * 4096;
#pragma unroll
    for (int it = 0; it < 2; ++it) {
      int chunk = wave * 2 + it;
      gld_lds16(A + (size_t)(m0 + chunk * 8 + rA) * 1024 + k0 + kcs, As + chunk * 512);
    }
  };
  auto stageB = [&](int k0, int buf) {
    u16* Bs = smem + 8192 + buf * 8192;
    const int k05 = k0 >> 5;
#pragma unroll
    for (int it = 0; it < 4; ++it) {
      int c = it * 4 + wave;
      int j = c >> 1, ks = c & 1;
      gld_lds16(Bf + (size_t)((n04 + j) * 32 + k05 + ks) * 512 + lane * 8, Bs + c * 512);
    }
  };

  f32x4 acc[2][4] = {};

  stageA(0, 0);
  stageB(0, 0);
  __syncthreads();

  for (int i = 0; i < 16; ++i) {
    const int k0 = i * 64;
    const int cur = i & 1;
    if (i < 15) { stageA(k0 + 64, cur ^ 1); stageB(k0 + 64, cur ^ 1); }
    const u16* As = smem + cur * 4096;
    const u16* Bs = smem + 8192 + cur * 8192;
    short8 bf[2][4];
#pragma unroll
    for (int ks = 0; ks < 2; ++ks)
#pragma unroll
      for (int ni = 0; ni < 4; ++ni)
        bf[ks][ni] = *(const short8*)(Bs + (size_t)((((wave & 1) * 4 + ni) * 2 + ks) * 512) + lane * 8);
#pragma unroll
    for (int ks = 0; ks < 2; ++ks) {
      short8 af[2];
#pragma unroll
      for (int mi = 0; mi < 2; ++mi) {
        int row = wr + mi * 16 + cl;
        af[mi] = *(const short8*)(As + (row >> 3) * 512 + r7 * 64 +
                                  (((ks << 2) | quad) ^ r7) * 8);
      }
#pragma unroll
      for (int mi = 0; mi < 2; ++mi)
#pragma unroll
        for (int ni = 0; ni < 4; ++ni)
          acc[mi][ni] = __builtin_amdgcn_mfma_f32_16x16x32_bf16(af[mi], bf[ks][ni], acc[mi][ni], 0, 0, 0);
    }
    __syncthreads();
  }
#pragma unroll
  for (int mi = 0; mi < 2; ++mi)
#pragma unroll
    for (int ni = 0; ni < 4; ++ni)
#pragma unroll
      for (int r = 0; r < 4; ++r) {
        int row = m0 + wr + mi * 16 + quad * 4 + r;
        int col = n0 + wc + ni * 16 + cl;
        Cm[(size_t)row * 1024 + col] = acc[mi][ni][r] + bias[col];
      }
}

// ---------- flash attention: 512 blocks x 512 thr (8 waves), 128 q/block ----------
// R3 structure (halved K/V DMA traffic). Unchanged this round.
__global__ __launch_bounds__(512, 4) void flash_attn(
    const u16* __restrict__ qb, const u16* __restrict__ kf,
    const u16* __restrict__ vf, u16* __restrict__ outp) {
  __shared__ __align__(16) u16 kv[2][16 * 512];    // [buf][K chunks 0-7 | V chunks 8-15]
  const int tid = threadIdx.x, lane = tid & 63, wave = tid >> 6;   // wave in [0,8)
  const int quad = lane >> 4, cl = lane & 15;
  const int id = blockIdx.x;                       // 512 blocks
  const int h = (id & 7) | (((id >> 3) & 1) << 3); // XCD-aware: id%8 = h%8
  const int b = (id >> 4) & 1;
  const int qt = id >> 5;                          // [0,16), 128 q rows each

  const int qrow0 = b * 2048 + qt * 128 + wave * 16;
  short8 bq[2];   // Q as B-operand: B[n=cl][k=quad*8+j]
#pragma unroll
  for (int ks = 0; ks < 2; ++ks)
    bq[ks] = *(const short8*)(qb + (size_t)(qrow0 + cl) * 1024 + h * 64 + ks * 32 + quad * 8);

  short8 ones;    // all-ones bf16 A-fragment for the l-MFMA
#pragma unroll
  for (int j = 0; j < 8; ++j) ones[j] = (short)0x3F80;

  const u16* kfb = kf + (size_t)((b * 16 + h) * 32) * 4096;
  const u16* vfb = vf + (size_t)((b * 16 + h) * 32) * 4096;

  // 16 chunks/tile, 8 waves -> 2 chunks per wave (c<8: K chunk c; else V c-8)
  auto stage = [&](int kt, int buf) {
#pragma unroll
    for (int i = 0; i < 2; ++i) {
      int c = wave * 2 + i;
      const u16* src = (c < 8) ? (kfb + (size_t)kt * 4096 + c * 512)
                               : (vfb + (size_t)kt * 4096 + (c - 8) * 512);
      gld_lds16(src + lane * 8, &kv[buf][c * 512]);
    }
  };

  f32x4 o_acc[4] = {};   // O^T: row d = nd*16+quad*4+r, col m = cl
  f32x4 l_acc = {};      // denominator: every row of D = sum_k P[k][cl]

  stage(0, 0);
  __syncthreads();

#pragma unroll 1
  for (int kt = 0; kt < 32; ++kt) {
    const int cur = kt & 1, nxt = cur ^ 1;
    if (kt < 31) stage(kt + 1, nxt);           // DMA overlaps this iter's compute
    const u16* kb = &kv[cur][0];
    const u16* vb = &kv[cur][8 * 512];
    f32x4 st[4] = {};
    __builtin_amdgcn_s_setprio(1);
#pragma unroll
    for (int ks = 0; ks < 2; ++ks)
#pragma unroll
      for (int ni = 0; ni < 4; ++ni) {
        short8 ak = *(const short8*)(kb + (ks * 4 + ni) * 512 + lane * 8);
        st[ni] = __builtin_amdgcn_mfma_f32_16x16x32_bf16(ak, bq[ks], st[ni], 0, 0, 0);
      }
    __builtin_amdgcn_s_setprio(0);
    // issue V-frag reads NOW: ~120cy LDS latency hides under the exp/pack VALU
    short8 av[2][4];
#pragma unroll
    for (int ks = 0; ks < 2; ++ks)
#pragma unroll
      for (int nd = 0; nd < 4; ++nd)
        av[ks][nd] = *(const short8*)(vb + (ks * 4 + nd) * 512 + lane * 8);
    u32 bp[2][4];
#pragma unroll
    for (int ni = 0; ni < 4; ++ni) {
      float p0 = __builtin_amdgcn_exp2f(st[ni][0]);
      float p1 = __builtin_amdgcn_exp2f(st[ni][1]);
      float p2 = __builtin_amdgcn_exp2f(st[ni][2]);
      float p3 = __builtin_amdgcn_exp2f(st[ni][3]);
      bp[ni >> 1][(ni & 1) * 2 + 0] = cvtpk2bf(p0, p1);
      bp[ni >> 1][(ni & 1) * 2 + 1] = cvtpk2bf(p2, p3);
    }
    __builtin_amdgcn_s_setprio(1);
#pragma unroll
    for (int ks = 0; ks < 2; ++ks) {
      short8 pb;
      *(u32*)&pb     = bp[ks][0];
      ((u32*)&pb)[1] = bp[ks][1];
      ((u32*)&pb)[2] = bp[ks][2];
      ((u32*)&pb)[3] = bp[ks][3];
#pragma unroll
      for (int nd = 0; nd < 4; ++nd)
        o_acc[nd] = __builtin_amdgcn_mfma_f32_16x16x32_bf16(av[ks][nd], pb, o_acc[nd], 0, 0, 0);
      // denominator on the matrix pipe: D[m][cl] += sum_k 1*P[k][cl]
      l_acc = __builtin_amdgcn_mfma_f32_16x16x32_bf16(ones, pb, l_acc, 0, 0, 0);
    }
    __builtin_amdgcn_s_setprio(0);
    __syncthreads();   // waves done reading cur; DMA(nxt) drained
  }
  float inv = 1.f / l_acc[0];   // all rows identical; lane holds col cl
  // per-wave scratch: 16 rows x 68 u16; 8 waves span kv[0]+kv[1] (dead now,
  // each wave reads only its own region -> no cross-wave hazard)
  u16* Ow = &kv[0][wave * 16 * 68];
#pragma unroll
  for (int nd = 0; nd < 4; ++nd)
#pragma unroll
    for (int r2 = 0; r2 < 2; ++r2)
      *(u32*)(Ow + cl * 68 + nd * 16 + quad * 4 + r2 * 2) =
          cvtpk2bf(o_acc[nd][r2 * 2] * inv, o_acc[nd][r2 * 2 + 1] * inv);
#pragma unroll
  for (int half = 0; half < 2; ++half) {
    int row = half * 8 + (lane >> 3);
    int d0 = (lane & 7) * 8;
    short8 ov = *(const short8*)(Ow + row * 68 + d0);
    *(short8*)(outp + (size_t)(qrow0 + row) * 1024 + h * 64 + d0) = ov;
  }
}

// ---------- launch ----------
extern "C" void kernel_launch(void* const* d_in, const int* in_sizes, int n_in,
                              void* d_out, int out_size, void* d_ws, size_t ws_size,
                              hipStream_t stream) {
  const float* query   = (const float*)d_in[0];
  const float* context = (const float*)d_in[1];
  const float* Wq  = (const float*)d_in[2];
  const float* bq  = (const float*)d_in[3];
  const float* Wkv = (const float*)d_in[4];
  const float* bkv = (const float*)d_in[5];
  const float* Wo  = (const float*)d_in[6];
  const float* bo  = (const float*)d_in[7];
  float* out = (float*)d_out;

  char* ws = (char*)d_ws;
  size_t off = 0;
  auto alloc = [&](size_t bytes) {
    char* p = ws + off;
    off += (bytes + 255) & ~(size_t)255;
    return p;
  };
  u16* buf0 = (u16*)alloc(4096ull * 1024 * 2);   // Xq -> attn_out
  u16* xcb  = (u16*)alloc(4096ull * 1024 * 2);   // Xc
  u16* WqF  = (u16*)alloc(1024ull * 1024 * 2);   // frag-major weights
  u16* WkvF = (u16*)alloc(2048ull * 1024 * 2);
  u16* WoF  = (u16*)alloc(1024ull * 1024 * 2);
  u16* qb   = (u16*)alloc(4096ull * 1024 * 2);
  u16* kfr  = (u16*)alloc(4ull * 1024 * 1024 * 2);
  u16* vfr  = (u16*)alloc(4ull * 1024 * 1024 * 2);

  const float QSCALE = 0.125f * 1.44269504f;  // 1/sqrt(64) * log2(e)

  pre_kernel<<<12288, dim3(32, 8), 0, stream>>>(query, context, Wq, Wkv, Wo,
                                                buf0, xcb, WqF, WkvF, WoF);
  qkv_gemm<<<768, 256, 0, stream>>>(buf0, xcb, WqF, WkvF, bq, bkv,
                                    qb, kfr, vfr, QSCALE);
  flash_attn<<<512, 512, 0, stream>>>(qb, kfr, vfr, buf0);
  o_gemm<<<512, 256, 0, stream>>>(buf0, WoF, bo, out);
}

// Round 7
// 180.959 us; speedup vs baseline: 1.0648x; 1.0095x over previous
//
#include <hip/hip_runtime.h>
#include <math.h>

typedef unsigned short u16;
typedef unsigned int u32;
typedef __attribute__((ext_vector_type(8))) short short8;
typedef __attribute__((ext_vector_type(4))) short short4v;
typedef __attribute__((ext_vector_type(4))) float f32x4;

// ---------- helpers ----------
__device__ __forceinline__ u16 f2bf(float f) {
  union { float f; unsigned u; } x; x.f = f;
  unsigned r = x.u + 0x7FFFu + ((x.u >> 16) & 1u);   // RNE
  return (u16)(r >> 16);
}

__device__ __forceinline__ u32 asu(float f) {
  union { float f; u32 u; } x; x.f = f; return x.u;
}

// pack two floats -> two bf16 (round-half-up) in one u32: lo=a, hi=b
__device__ __forceinline__ u32 pack2bf(float a, float b) {
  return __builtin_amdgcn_perm(asu(b) + 0x8000u, asu(a) + 0x8000u, 0x07060302u);
}

// single-instruction packed f32->bf16 (RNE), lo=a hi=b  [T12 primitive]
__device__ __forceinline__ u32 cvtpk2bf(float a, float b) {
  u32 r;
  asm("v_cvt_pk_bf16_f32 %0, %1, %2" : "=v"(r) : "v"(a), "v"(b));
  return r;
}

__device__ __forceinline__ void gld_lds16(const void* g, void* l) {
  __builtin_amdgcn_global_load_lds(
      (const __attribute__((address_space(1))) unsigned int*)g,
      (__attribute__((address_space(3))) unsigned int*)l, 16, 0, 0);
}

// ---------- fused preprocessing ----------
// cast Xq/Xc row-major bf16 + convert weights to FRAGMENT-MAJOR bf16.
// Chunk (n4=n>>4, k5=k>>5) at ((n4*32)+k5)*512; within chunk element (n,k):
// addr = (k>>3)*128 + (n&15)*8 + (k&7)  (verified R11).
__global__ void pre_kernel(const float* __restrict__ q, const float* __restrict__ c,
                           const float* __restrict__ Wq, const float* __restrict__ Wkv,
                           const float* __restrict__ Wo,
                           u16* __restrict__ xq, u16* __restrict__ xc,
                           u16* __restrict__ WqF, u16* __restrict__ WkvF,
                           u16* __restrict__ WoF) {
  __shared__ float tile[32][33];
  int bx = blockIdx.x;
  int t = threadIdx.y * 32 + threadIdx.x;
  if (bx < 8192) {
    int i = bx * 256 + t;
    const float* src = q; u16* dst = xq;
    if (i >= 1048576) { i -= 1048576; src = c; dst = xc; }
    float4 v = ((const float4*)src)[i];
    ((uint2*)dst)[i] = make_uint2(
        (unsigned)f2bf(v.x) | ((unsigned)f2bf(v.y) << 16),
        (unsigned)f2bf(v.z) | ((unsigned)f2bf(v.w) << 16));
  } else {
    int g = bx - 8192;
    int gx = g & 127, gy = g >> 7;               // gy = k-tile in [0,32)
    const float* src; u16* dst; int N, n0;
    if (gx < 32)      { src = Wq;  dst = WqF;  N = 1024; n0 = gx * 32; }
    else if (gx < 96) { src = Wkv; dst = WkvF; N = 2048; n0 = (gx - 32) * 32; }
    else              { src = Wo;  dst = WoF;  N = 1024; n0 = (gx - 96) * 32; }
    int k0 = gy * 32;
    int tx = threadIdx.x, ty = threadIdx.y;      // (32,8)
#pragma unroll
    for (int i = 0; i < 4; ++i)
      tile[ty * 4 + i][tx] = src[(size_t)(k0 + ty * 4 + i) * N + n0 + tx];
    __syncthreads();
    int e = t * 4;
    int ch = e >> 9, rem = e & 511;
    int kg = (rem >> 7) & 3;          // k-group of 8
    int nl = (rem >> 3) & 15;         // n within 16
    int j0 = rem & 7;                 // 0 or 4
    int kk = kg * 8 + j0;
    int nn = ch * 16 + nl;
    u32 lo = pack2bf(tile[kk][nn], tile[kk + 1][nn]);
    u32 hi = pack2bf(tile[kk + 2][nn], tile[kk + 3][nn]);
    *(uint2*)(dst + (size_t)(((n0 >> 4) + ch) * 32 + gy) * 512 + rem) = make_uint2(lo, hi);
  }
}

// ---------- fused QKV GEMM: 768 blocks (3/CU resident), 256 thr, 128x128 ----------
// R6 (measured win): BK=64, A dbuf LDS, B software-pipelined into registers,
// XCD remap. Unchanged this round.
__global__ __launch_bounds__(256, 3) void qkv_gemm(
    const u16* __restrict__ Xq, const u16* __restrict__ Xc,
    const u16* __restrict__ WqF, const u16* __restrict__ WkvF,
    const float* __restrict__ bq, const float* __restrict__ bkv,
    u16* __restrict__ qb, u16* __restrict__ kf, u16* __restrict__ vf,
    float qscale) {
  __shared__ __align__(16) u16 smem[16896];      // K-loop: As dbuf 2x8192 / epilogue: C-tile
  const int tid = threadIdx.x, lane = tid & 63, wave = tid >> 6;
  const int quad = lane >> 4, cl = lane & 15;
  const int wr = (wave >> 1) * 64, wc = (wave & 1) * 64;

  // XCD-aware 2D remap (assumes xcd = blockIdx.x % 8; bijective on 768)
  const int xcd = blockIdx.x & 7, pos = blockIdx.x >> 3;   // pos in [0,96)
  const u16 *A, *Bf; const float* bias; int m0, n0; bool isq;
  if (pos < 64) {   // KV chunk: 8m x 8n per XCD
    isq = false; A = Xc; Bf = WkvF; bias = bkv;
    m0 = ((xcd >> 1) * 8 + (pos >> 3)) * 128;
    n0 = ((xcd & 1) * 8 + (pos & 7)) * 128;
  } else {          // Q chunk: 4m x 8n per XCD
    int p = pos - 64;
    isq = true;  A = Xq; Bf = WqF;  bias = bq;
    m0 = (xcd * 4 + (p >> 3)) * 128;
    n0 = (p & 7) * 128;
  }
  const int bn4 = (n0 + wc) >> 4;

  const int rA = lane >> 3;
  const int kcs = ((lane & 7) ^ rA) * 8;         // swizzled source k within 64
  const int r7 = cl & 7;                          // reader row&7

  // stage BK=64 A-tile for k0 into buffer buf (16 chunks, 4/wave)
  auto stageA = [&](int k0, int buf) {
    u16* As = smem + buf * 8192;
#pragma unroll
    for (int it = 0; it < 4; ++it) {
      int chunk = it * 4 + wave;
      gld_lds16(A + (size_t)(m0 + chunk * 8 + rA) * 1024 + k0 + kcs, As + chunk * 512);
    }
  };

  f32x4 acc[4][4] = {};
  short8 bA[2][4], bB[2][4];

  // B-frag register prefetch for k-tile k05 (=k0>>5)
  auto loadB = [&](short8 (&dst)[2][4], int k05) {
#pragma unroll
    for (int ks = 0; ks < 2; ++ks)
#pragma unroll
      for (int ni = 0; ni < 4; ++ni)
        dst[ks][ni] = *(const short8*)(Bf + (size_t)((bn4 + ni) * 32 + k05 + ks) * 512 + lane * 8);
  };

  auto compute = [&](const u16* As, short8 (&breg)[2][4]) {
#pragma unroll
    for (int ks = 0; ks < 2; ++ks) {
      short8 af[4];
#pragma unroll
      for (int mi = 0; mi < 4; ++mi) {
        int row = wr + mi * 16 + cl;
        af[mi] = *(const short8*)(As + (row >> 3) * 512 + r7 * 64 +
                                  (((ks << 2) | quad) ^ r7) * 8);
      }
#pragma unroll
      for (int mi = 0; mi < 4; ++mi)
#pragma unroll
        for (int ni = 0; ni < 4; ++ni)
          acc[mi][ni] = __builtin_amdgcn_mfma_f32_16x16x32_bf16(af[mi], breg[ks][ni], acc[mi][ni], 0, 0, 0);
    }
  };

  stageA(0, 0);
  loadB(bA, 0);
  __syncthreads();                               // drain stage0

#pragma unroll 1
  for (int ii = 0; ii < 8; ++ii) {
    const int i = ii * 2;
    // even iter: consume bA from buf0; prefetch iter i+1 (A->LDS buf1, B->bB)
    stageA((i + 1) * 64, 1);
    loadB(bB, (i + 1) * 2);
    compute(smem, bA);
    __syncthreads();   // reads of buf0 done; DMA(buf1)+bB drained
    // odd iter: consume bB from buf1; prefetch iter i+2 (A->LDS buf0, B->bA)
    const int j = i + 1;
    if (j < 15) { stageA((j + 1) * 64, 0); loadB(bA, (j + 1) * 2); }
    compute(smem + 8192, bB);
    __syncthreads();   // reads of buf1 done; DMA(buf0)+bA drained
  }

  if (isq) {
#pragma unroll
    for (int mi = 0; mi < 4; ++mi)
#pragma unroll
      for (int ni = 0; ni < 4; ++ni)
#pragma unroll
        for (int r = 0; r < 4; ++r) {
          int row = m0 + wr + mi * 16 + quad * 4 + r;
          int col = n0 + wc + ni * 16 + cl;
          qb[(size_t)row * 1024 + col] = f2bf((acc[mi][ni][r] + bias[col]) * qscale);
        }
    return;
  }

  const int b = m0 >> 11, kt0 = (m0 & 2047) >> 6;
  const bool kreg = (n0 < 1024);
  if (kreg) {
    // K-tile -> LDS [t][d], stride 132 (scalar b16 stores; b128 frag reads)
#pragma unroll
    for (int mi = 0; mi < 4; ++mi)
#pragma unroll
      for (int ni = 0; ni < 4; ++ni)
#pragma unroll
        for (int r = 0; r < 4; ++r)
          smem[(wr + mi * 16 + quad * 4 + r) * 132 + wc + ni * 16 + cl] =
              f2bf(acc[mi][ni][r] + bias[n0 + wc + ni * 16 + cl]);
    __syncthreads();
#pragma unroll
    for (int i = 0; i < 8; ++i) {
      int c = i * 4 + wave;                       // 32 chunks
      int hs = c >> 4, ts = (c >> 3) & 1, ks = (c >> 2) & 1, idx = c & 3;
      int h = (n0 >> 6) + hs;
      size_t bhkt = ((size_t)((b * 16 + h) * 32 + kt0 + ts)) * 4096;
      short8 v = *(const short8*)(smem + (ts * 64 + idx * 16 + cl) * 132 +
                                  hs * 64 + ks * 32 + quad * 8);
      *(short8*)(kf + bhkt + (size_t)(ks * 4 + idx) * 512 + lane * 8) = v;
    }
  } else {
    // V-tile -> LDS transposed [d][t], stride 132, then emit relabeled V^T A-frags
#pragma unroll
    for (int mi = 0; mi < 4; ++mi)
#pragma unroll
      for (int ni = 0; ni < 4; ++ni) {
        float v0 = acc[mi][ni][0] + bias[n0 + wc + ni * 16 + cl];
        float v1 = acc[mi][ni][1] + bias[n0 + wc + ni * 16 + cl];
        float v2 = acc[mi][ni][2] + bias[n0 + wc + ni * 16 + cl];
        float v3 = acc[mi][ni][3] + bias[n0 + wc + ni * 16 + cl];
        *(uint2*)(smem + (wc + ni * 16 + cl) * 132 + wr + mi * 16 + quad * 4) =
            make_uint2(pack2bf(v0, v1), pack2bf(v2, v3));
      }
    __syncthreads();
#pragma unroll
    for (int i = 0; i < 8; ++i) {
      int c = i * 4 + wave;
      int hs = c >> 4, ts = (c >> 3) & 1, ks = (c >> 2) & 1, idx = c & 3;
      int h = ((n0 - 1024) >> 6) + hs;
      size_t bhkt = ((size_t)((b * 16 + h) * 32 + kt0 + ts)) * 4096;
      // k-slot j<4: t = ts*64 + ks*32 + quad*4 + j ; j>=4: +16
      const u16* src = smem + (hs * 64 + idx * 16 + cl) * 132 + ts * 64 + ks * 32 + quad * 4;
      short8 v;
      *(short4v*)&v       = *(const short4v*)(src);
      *((short4v*)&v + 1) = *(const short4v*)(src + 16);
      *(short8*)(vf + bhkt + (size_t)(ks * 4 + idx) * 512 + lane * 8) = v;
    }
  }
}

// ---------- O-proj: 512 blocks, 256 thr, 64x128 tiles ----------
// R2 (measured win): B staged via gld_lds dbuf + XCD remap. Unchanged.
__global__ __launch_bounds__(256) void o_gemm(
    const u16* __restrict__ A, const u16* __restrict__ Bf,
    const float* __restrict__ bias, float* __restrict__ Cm) {
  __shared__ __align__(16) u16 smem[24576];   // [0,8192): A dbuf | [8192,24576): B dbuf
  const int tid = threadIdx.x, lane = tid & 63, wave = tid >> 6;
  const int quad = lane >> 4, cl = lane & 15;
  const int xcd = blockIdx.x & 7, pos = blockIdx.x >> 3;   // pos in [0,64)
  const int m0 = (xcd * 8 + (pos >> 3)) * 64, n0 = (pos & 7) * 128;
  const int wr = (wave >> 1) * 32, wc = (wave & 1) * 64;
  const int n04 = n0 >> 4;

  const int rA = lane >> 3;
  const int kcs = ((lane & 7) ^ rA) * 8;
  const int r7 = cl & 7;

  auto stageA = [&](int k0, int buf) {
    u16* As = smem + buf * 4096;
#pragma unroll
    for (int it = 0; it < 2; ++it) {
      int chunk = wave * 2 + it;
      gld_lds16(A + (size_t)(m0 + chunk * 8 + rA) * 1024 + k0 + kcs, As + chunk * 512);
    }
  };
  auto stageB = [&](int k0, int buf) {
    u16* Bs = smem + 8192 + buf * 8192;
    const int k05 = k0 >> 5;
#pragma unroll
    for (int it = 0; it < 4; ++it) {
      int c = it * 4 + wave;
      int j = c >> 1, ks = c & 1;
      gld_lds16(Bf + (size_t)((n04 + j) * 32 + k05 + ks) * 512 + lane * 8, Bs + c * 512);
    }
  };

  f32x4 acc[2][4] = {};

  stageA(0, 0);
  stageB(0, 0);
  __syncthreads();

  for (int i = 0; i < 16; ++i) {
    const int k0 = i * 64;
    const int cur = i & 1;
    if (i < 15) { stageA(k0 + 64, cur ^ 1); stageB(k0 + 64, cur ^ 1); }
    const u16* As = smem + cur * 4096;
    const u16* Bs = smem + 8192 + cur * 8192;
    short8 bf[2][4];
#pragma unroll
    for (int ks = 0; ks < 2; ++ks)
#pragma unroll
      for (int ni = 0; ni < 4; ++ni)
        bf[ks][ni] = *(const short8*)(Bs + (size_t)((((wave & 1) * 4 + ni) * 2 + ks) * 512) + lane * 8);
#pragma unroll
    for (int ks = 0; ks < 2; ++ks) {
      short8 af[2];
#pragma unroll
      for (int mi = 0; mi < 2; ++mi) {
        int row = wr + mi * 16 + cl;
        af[mi] = *(const short8*)(As + (row >> 3) * 512 + r7 * 64 +
                                  (((ks << 2) | quad) ^ r7) * 8);
      }
#pragma unroll
      for (int mi = 0; mi < 2; ++mi)
#pragma unroll
        for (int ni = 0; ni < 4; ++ni)
          acc[mi][ni] = __builtin_amdgcn_mfma_f32_16x16x32_bf16(af[mi], bf[ks][ni], acc[mi][ni], 0, 0, 0);
    }
    __syncthreads();
  }
#pragma unroll
  for (int mi = 0; mi < 2; ++mi)
#pragma unroll
    for (int ni = 0; ni < 4; ++ni)
#pragma unroll
      for (int r = 0; r < 4; ++r) {
        int row = m0 + wr + mi * 16 + quad * 4 + r;
        int col = n0 + wc + ni * 16 + cl;
        Cm[(size_t)row * 1024 + col] = acc[mi][ni][r] + bias[col];
      }
}

// ---------- flash attention: 512 blocks x 256 thr (4 waves), 32 q/wave ----------
// R7: m214-style fat waves. Each wave owns TWO 16-row q-sets -> 2 independent
// QK/exp/PV chains in registers (intra-wave ILP fills MFMA+exp latency);
// each K-fragment ds_read feeds 2 MFMAs. 2 blocks/CU with INDEPENDENT
// barriers -> anti-phase execution across blocks (one block's exp overlaps
// the other's MFMA). 2 waves/SIMD (VGPR ~200).
__global__ __launch_bounds__(256, 2) void flash_attn(
    const u16* __restrict__ qb, const u16* __restrict__ kf,
    const u16* __restrict__ vf, u16* __restrict__ outp) {
  __shared__ __align__(16) u16 kv[2][16 * 512];    // [buf][K chunks 0-7 | V chunks 8-15]
  const int tid = threadIdx.x, lane = tid & 63, wave = tid >> 6;   // wave in [0,4)
  const int quad = lane >> 4, cl = lane & 15;
  const int id = blockIdx.x;                       // 512 blocks
  const int h = (id & 7) | (((id >> 3) & 1) << 3); // XCD-aware: id%8 = h%8
  const int b = (id >> 4) & 1;
  const int qt = id >> 5;                          // [0,16), 128 q rows each

  const int qrow0 = b * 2048 + qt * 128 + wave * 32;   // 32 rows per wave
  short8 bq0[2], bq1[2];   // Q as B-operand for the two 16-row sets
#pragma unroll
  for (int ks = 0; ks < 2; ++ks) {
    bq0[ks] = *(const short8*)(qb + (size_t)(qrow0 + cl) * 1024 + h * 64 + ks * 32 + quad * 8);
    bq1[ks] = *(const short8*)(qb + (size_t)(qrow0 + 16 + cl) * 1024 + h * 64 + ks * 32 + quad * 8);
  }

  short8 ones;    // all-ones bf16 A-fragment for the l-MFMA
#pragma unroll
  for (int j = 0; j < 8; ++j) ones[j] = (short)0x3F80;

  const u16* kfb = kf + (size_t)((b * 16 + h) * 32) * 4096;
  const u16* vfb = vf + (size_t)((b * 16 + h) * 32) * 4096;

  // 16 chunks/tile, 4 waves -> 4 chunks per wave (c<8: K chunk c; else V c-8)
  auto stage = [&](int kt, int buf) {
#pragma unroll
    for (int i = 0; i < 4; ++i) {
      int c = wave * 4 + i;
      const u16* src = (c < 8) ? (kfb + (size_t)kt * 4096 + c * 512)
                               : (vfb + (size_t)kt * 4096 + (c - 8) * 512);
      gld_lds16(src + lane * 8, &kv[buf][c * 512]);
    }
  };

  f32x4 o0[4] = {}, o1[4] = {};   // O^T per set: row d = nd*16+quad*4+r, col m = cl
  f32x4 l0 = {}, l1 = {};         // denominators

  stage(0, 0);
  __syncthreads();

#pragma unroll 1
  for (int kt = 0; kt < 32; ++kt) {
    const int cur = kt & 1;
    if (kt < 31) stage(kt + 1, cur ^ 1);         // DMA overlaps this iter's compute
    const u16* kb = &kv[cur][0];
    const u16* vb = &kv[cur][8 * 512];
    f32x4 s0[4] = {}, s1[4] = {};
    __builtin_amdgcn_s_setprio(1);
#pragma unroll
    for (int ks = 0; ks < 2; ++ks)
#pragma unroll
      for (int ni = 0; ni < 4; ++ni) {
        short8 ak = *(const short8*)(kb + (ks * 4 + ni) * 512 + lane * 8);
        s0[ni] = __builtin_amdgcn_mfma_f32_16x16x32_bf16(ak, bq0[ks], s0[ni], 0, 0, 0);
        s1[ni] = __builtin_amdgcn_mfma_f32_16x16x32_bf16(ak, bq1[ks], s1[ni], 0, 0, 0);
      }
    __builtin_amdgcn_s_setprio(0);
    // issue V-frag reads NOW: LDS latency hides under the exp/pack VALU
    short8 av[2][4];
#pragma unroll
    for (int ks = 0; ks < 2; ++ks)
#pragma unroll
      for (int nd = 0; nd < 4; ++nd)
        av[ks][nd] = *(const short8*)(vb + (ks * 4 + nd) * 512 + lane * 8);
    u32 bp0[2][4], bp1[2][4];
#pragma unroll
    for (int ni = 0; ni < 4; ++ni) {
      float a0 = __builtin_amdgcn_exp2f(s0[ni][0]);
      float a1 = __builtin_amdgcn_exp2f(s0[ni][1]);
      float a2 = __builtin_amdgcn_exp2f(s0[ni][2]);
      float a3 = __builtin_amdgcn_exp2f(s0[ni][3]);
      bp0[ni >> 1][(ni & 1) * 2 + 0] = cvtpk2bf(a0, a1);
      bp0[ni >> 1][(ni & 1) * 2 + 1] = cvtpk2bf(a2, a3);
      float c0 = __builtin_amdgcn_exp2f(s1[ni][0]);
      float c1 = __builtin_amdgcn_exp2f(s1[ni][1]);
      float c2 = __builtin_amdgcn_exp2f(s1[ni][2]);
      float c3 = __builtin_amdgcn_exp2f(s1[ni][3]);
      bp1[ni >> 1][(ni & 1) * 2 + 0] = cvtpk2bf(c0, c1);
      bp1[ni >> 1][(ni & 1) * 2 + 1] = cvtpk2bf(c2, c3);
    }
    __builtin_amdgcn_s_setprio(1);
#pragma unroll
    for (int ks = 0; ks < 2; ++ks) {
      short8 pb0, pb1;
      *(u32*)&pb0     = bp0[ks][0];
      ((u32*)&pb0)[1] = bp0[ks][1];
      ((u32*)&pb0)[2] = bp0[ks][2];
      ((u32*)&pb0)[3] = bp0[ks][3];
      *(u32*)&pb1     = bp1[ks][0];
      ((u32*)&pb1)[1] = bp1[ks][1];
      ((u32*)&pb1)[2] = bp1[ks][2];
      ((u32*)&pb1)[3] = bp1[ks][3];
#pragma unroll
      for (int nd = 0; nd < 4; ++nd) {
        o0[nd] = __builtin_amdgcn_mfma_f32_16x16x32_bf16(av[ks][nd], pb0, o0[nd], 0, 0, 0);
        o1[nd] = __builtin_amdgcn_mfma_f32_16x16x32_bf16(av[ks][nd], pb1, o1[nd], 0, 0, 0);
      }
      l0 = __builtin_amdgcn_mfma_f32_16x16x32_bf16(ones, pb0, l0, 0, 0, 0);
      l1 = __builtin_amdgcn_mfma_f32_16x16x32_bf16(ones, pb1, l1, 0, 0, 0);
    }
    __builtin_amdgcn_s_setprio(0);
    __syncthreads();   // waves done reading cur; DMA(nxt) drained
  }
  float inv0 = 1.f / l0[0], inv1 = 1.f / l1[0];
  // per-wave scratch: 32 rows x 68 u16 (4 waves x 2176 u16 = 8704 <= 16384)
  u16* Ow = &kv[0][wave * 32 * 68];
#pragma unroll
  for (int nd = 0; nd < 4; ++nd)
#pragma unroll
    for (int r2 = 0; r2 < 2; ++r2) {
      *(u32*)(Ow + cl * 68 + nd * 16 + quad * 4 + r2 * 2) =
          cvtpk2bf(o0[nd][r2 * 2] * inv0, o0[nd][r2 * 2 + 1] * inv0);
      *(u32*)(Ow + (16 + cl) * 68 + nd * 16 + quad * 4 + r2 * 2) =
          cvtpk2bf(o1[nd][r2 * 2] * inv1, o1[nd][r2 * 2 + 1] * inv1);
    }
#pragma unroll
  for (int p = 0; p < 4; ++p) {
    int row = p * 8 + (lane >> 3);               // [0,32)
    int d0 = (lane & 7) * 8;
    short8 ov = *(const short8*)(Ow + row * 68 + d0);
    *(short8*)(outp + (size_t)(qrow0 + row) * 1024 + h * 64 + d0) = ov;
  }
}

// ---------- launch ----------
extern "C" void kernel_launch(void* const* d_in, const int* in_sizes, int n_in,
                              void* d_out, int out_size, void* d_ws, size_t ws_size,
                              hipStream_t stream) {
  const float* query   = (const float*)d_in[0];
  const float* context = (const float*)d_in[1];
  const float* Wq  = (const float*)d_in[2];
  const float* bq  = (const float*)d_in[3];
  const float* Wkv = (const float*)d_in[4];
  const float* bkv = (const float*)d_in[5];
  const float* Wo  = (const float*)d_in[6];
  const float* bo  = (const float*)d_in[7];
  float* out = (float*)d_out;

  char* ws = (char*)d_ws;
  size_t off = 0;
  auto alloc = [&](size_t bytes) {
    char* p = ws + off;
    off += (bytes + 255) & ~(size_t)255;
    return p;
  };
  u16* buf0 = (u16*)alloc(4096ull * 1024 * 2);   // Xq -> attn_out
  u16* xcb  = (u16*)alloc(4096ull * 1024 * 2);   // Xc
  u16* WqF  = (u16*)alloc(1024ull * 1024 * 2);   // frag-major weights
  u16* WkvF = (u16*)alloc(2048ull * 1024 * 2);
  u16* WoF  = (u16*)alloc(1024ull * 1024 * 2);
  u16* qb   = (u16*)alloc(4096ull * 1024 * 2);
  u16* kfr  = (u16*)alloc(4ull * 1024 * 1024 * 2);
  u16* vfr  = (u16*)alloc(4ull * 1024 * 1024 * 2);

  const float QSCALE = 0.125f * 1.44269504f;  // 1/sqrt(64) * log2(e)

  pre_kernel<<<12288, dim3(32, 8), 0, stream>>>(query, context, Wq, Wkv, Wo,
                                                buf0, xcb, WqF, WkvF, WoF);
  qkv_gemm<<<768, 256, 0, stream>>>(buf0, xcb, WqF, WkvF, bq, bkv,
                                    qb, kfr, vfr, QSCALE);
  flash_attn<<<512, 256, 0, stream>>>(qb, kfr, vfr, buf0);
  o_gemm<<<512, 256, 0, stream>>>(buf0, WoF, bo, out);
}